// Round 3
// baseline (158.339 us; speedup 1.0000x reference)
//
#include <hip/hip_runtime.h>
#include <cstdint>

#define FP8MAX 448.0f

typedef float f32x4 __attribute__((ext_vector_type(4)));
typedef int   i32x4 __attribute__((ext_vector_type(4)));
typedef int   i32x8 __attribute__((ext_vector_type(8)));

union frag8 { i32x8 v8; i32x4 v4[2]; };

__device__ __forceinline__ void gload_lds16(const void* g, void* l) {
  __builtin_amdgcn_global_load_lds(
      (const __attribute__((address_space(1))) unsigned int*)g,
      (__attribute__((address_space(3))) unsigned int*)l,
      16, 0, 0);
}

// ---------- quantize x rows: H=2048 floats -> fp8 bytes + per-128-group inv_scale ----------
__global__ __launch_bounds__(256) void quant_x(const float* __restrict__ x,
                                               uint8_t* __restrict__ xq,
                                               float* __restrict__ sa) {
  const int m = blockIdx.x;
  const int t = threadIdx.x;
  const float* xr = x + (size_t)m * 2048;
  float4 v0 = ((const float4*)xr)[t * 2];
  float4 v1 = ((const float4*)xr)[t * 2 + 1];
  float amax = fmaxf(fmaxf(fmaxf(fabsf(v0.x), fabsf(v0.y)), fmaxf(fabsf(v0.z), fabsf(v0.w))),
                     fmaxf(fmaxf(fabsf(v1.x), fabsf(v1.y)), fmaxf(fabsf(v1.z), fabsf(v1.w))));
  #pragma unroll
  for (int off = 1; off < 16; off <<= 1)
    amax = fmaxf(amax, __shfl_xor(amax, off));
  amax = fmaxf(amax, 1e-12f);
  float s   = FP8MAX / amax;   // same op order as reference
  float inv = 1.0f / s;
  if ((t & 15) == 0) sa[(size_t)m * 16 + (t >> 4)] = inv;
  float q[8] = {v0.x * s, v0.y * s, v0.z * s, v0.w * s,
                v1.x * s, v1.y * s, v1.z * s, v1.w * s};
  #pragma unroll
  for (int i = 0; i < 8; ++i) q[i] = fminf(fmaxf(q[i], -FP8MAX), FP8MAX);
  union { unsigned long long u; unsigned int w[2]; } pk;
  pk.w[0] = __builtin_amdgcn_cvt_pk_fp8_f32(q[0], q[1], 0, false);
  pk.w[0] = __builtin_amdgcn_cvt_pk_fp8_f32(q[2], q[3], pk.w[0], true);
  pk.w[1] = __builtin_amdgcn_cvt_pk_fp8_f32(q[4], q[5], 0, false);
  pk.w[1] = __builtin_amdgcn_cvt_pk_fp8_f32(q[6], q[7], pk.w[1], true);
  ((unsigned long long*)(xq + (size_t)m * 2048))[t] = pk.u;
}

// ---------- weight f32 -> fp8 (values are exactly fp8-representable; cast is exact) ----------
__global__ __launch_bounds__(256) void conv_w(const float* __restrict__ w,
                                              uint8_t* __restrict__ w8, int n8) {
  int i = blockIdx.x * 256 + threadIdx.x;
  if (i >= n8) return;
  float4 v0 = ((const float4*)w)[i * 2];
  float4 v1 = ((const float4*)w)[i * 2 + 1];
  union { unsigned long long u; unsigned int x[2]; } pk;
  pk.x[0] = __builtin_amdgcn_cvt_pk_fp8_f32(v0.x, v0.y, 0, false);
  pk.x[0] = __builtin_amdgcn_cvt_pk_fp8_f32(v0.z, v0.w, pk.x[0], true);
  pk.x[1] = __builtin_amdgcn_cvt_pk_fp8_f32(v1.x, v1.y, 0, false);
  pk.x[1] = __builtin_amdgcn_cvt_pk_fp8_f32(v1.z, v1.w, pk.x[1], true);
  ((unsigned long long*)w8)[i] = pk.u;
}

// ---------- block-scaled fp8 GEMM, 256x256 tile, 8 waves, 4-phase pipelined K-loop ----------
#define SAL_STRIDE 264

__global__ __launch_bounds__(512, 2) void gemm_fp8(
    const uint8_t* __restrict__ A, const uint8_t* __restrict__ Bw,
    const float* __restrict__ sa, const float* __restrict__ sb,
    const float* __restrict__ bias, float* __restrict__ out,
    int M, int N, int K) {
  const int J = K >> 7;               // 16
  const int nbn = N >> 8;             // 8
  int bid = blockIdx.x;
  int nwg = gridDim.x;
  if ((nwg & 7) == 0) {               // T1 XCD chunked swizzle (512 % 8 == 0)
    int cpx = nwg >> 3;
    bid = (bid & 7) * cpx + (bid >> 3);
  }
  const int bn = bid % nbn;
  const int bm = bid / nbn;
  const int t = threadIdx.x;
  const int lane = t & 63;
  const int w = t >> 6;
  const int wr = w >> 2;              // 0..1  (M band)
  const int wc = w & 3;               // 0..3  (N band)
  const int r16 = lane & 15;
  const int kg = lane >> 4;

  __shared__ __align__(16) uint8_t lA[2][256 * 128];
  __shared__ __align__(16) uint8_t lB[2][256 * 128];
  __shared__ __align__(16) float sal[16 * SAL_STRIDE];

  const uint8_t* gA = A + (size_t)bm * 256 * K;
  const uint8_t* gB = Bw + (size_t)bn * 256 * K;

  // stage inv_scale slab [j][row], 16B-aligned quads (stride 264 % 4 == 0)
  for (int i = t; i < 256 * 16; i += 512) {
    int row = i >> 4, j = i & 15;
    sal[j * SAL_STRIDE + row] = sa[((size_t)bm * 256 + row) * 16 + j];
  }

  const int rl = t >> 3;     // 0..63
  const int sg = t & 7;      // 16B segment

  // stage one half (128 rows x 128B = 16KB) = 2 gload_lds per thread
  #define STAGE(larr, gbase, h_, kt_) do {                                   \
    _Pragma("unroll")                                                        \
    for (int it_ = 0; it_ < 2; ++it_) {                                      \
      int r_ = it_ * 64 + rl;                                                \
      int grow_ = (h_) * 128 + r_;                                           \
      gload_lds16(gbase + (size_t)grow_ * K + (size_t)(kt_) * 128 +          \
                      ((sg ^ (r_ & 7)) << 4),                                \
                  &larr[grow_ * 128 + sg * 16]);                             \
    } } while (0)

  __syncthreads();   // sal visible to all; also drains nothing else yet

  // prologue: tile 0, issue order Ah0, Bh0, Bh1, Ah1 (matches steady-state queue)
  STAGE(lA[0], gA, 0, 0);
  STAGE(lB[0], gB, 0, 0);
  STAGE(lB[0], gB, 1, 0);
  STAGE(lA[0], gA, 1, 0);

  f32x4 tot[8][4] = {};
  const f32x4 fz = {0.f, 0.f, 0.f, 0.f};
  frag8 av[4], bv[2][2];
  f32x4 scq[4];

  #define BARSEQ(NN) do {                                                    \
    asm volatile("s_waitcnt vmcnt(" #NN ")" ::: "memory");                   \
    __builtin_amdgcn_s_barrier();                                            \
    asm volatile("" ::: "memory"); } while (0)

  #define READ_A(mg_, cur_) do { _Pragma("unroll")                           \
    for (int i_ = 0; i_ < 4; ++i_) {                                         \
      int row_ = (mg_) * 128 + wr * 64 + i_ * 16 + r16;                      \
      const uint8_t* bp_ = &lA[cur_][row_ * 128];                            \
      int sw_ = (row_ & 7) << 4;                                             \
      av[i_].v4[0] = *(const i32x4*)(bp_ + ((kg * 32) ^ sw_));               \
      av[i_].v4[1] = *(const i32x4*)(bp_ + ((kg * 32 + 16) ^ sw_));          \
    } } while (0)

  #define READ_B(ng_, cur_) do { _Pragma("unroll")                           \
    for (int j_ = 0; j_ < 2; ++j_) {                                         \
      int row_ = (ng_) * 128 + wc * 32 + j_ * 16 + r16;                      \
      const uint8_t* bp_ = &lB[cur_][row_ * 128];                            \
      int sw_ = (row_ & 7) << 4;                                             \
      bv[ng_][j_].v4[0] = *(const i32x4*)(bp_ + ((kg * 32) ^ sw_));          \
      bv[ng_][j_].v4[1] = *(const i32x4*)(bp_ + ((kg * 32 + 16) ^ sw_));     \
    } } while (0)

  #define CALC_SC(mg_, kt_, sbj_) do { _Pragma("unroll")                     \
    for (int i_ = 0; i_ < 4; ++i_) {                                         \
      scq[i_] = (*(const f32x4*)&sal[(kt_) * SAL_STRIDE + (mg_) * 128 +      \
                                     wr * 64 + i_ * 16 + kg * 4]) * (sbj_);  \
    } } while (0)

  #define MFMA8(mg_, ng_) do {                                               \
    __builtin_amdgcn_s_setprio(1);                                           \
    _Pragma("unroll")                                                        \
    for (int i_ = 0; i_ < 4; ++i_) { _Pragma("unroll")                       \
      for (int j_ = 0; j_ < 2; ++j_) {                                       \
        f32x4 p_ = __builtin_amdgcn_mfma_scale_f32_16x16x128_f8f6f4(         \
            av[i_].v8, bv[ng_][j_].v8, fz, 0, 0, 0, 0x7f7f7f7f, 0,           \
            0x7f7f7f7f);                                                     \
        tot[(mg_) * 4 + i_][(ng_) * 2 + j_] += p_ * scq[i_];                 \
      } }                                                                    \
    __builtin_amdgcn_s_setprio(0); } while (0)

  const int KT = K >> 7;   // 16
  for (int kt = 0; kt < KT - 1; ++kt) {
    const int cur = kt & 1, nxt = cur ^ 1;
    const float sb0 = sb[(bn * 2 + 0) * J + kt];
    const float sb1 = sb[(bn * 2 + 1) * J + kt];
    // ph0: needs Ah0,Bh0 of kt  | stages Ah0 of kt+1
    BARSEQ(4);
    READ_A(0, cur); READ_B(0, cur);
    STAGE(lA[nxt], gA, 0, kt + 1);
    CALC_SC(0, kt, sb0);
    MFMA8(0, 0);
    // ph1: needs Bh1 of kt      | stages Bh0 of kt+1
    BARSEQ(4);
    READ_B(1, cur);
    STAGE(lB[nxt], gB, 0, kt + 1);
    CALC_SC(0, kt, sb1);
    MFMA8(0, 1);
    // ph2: needs Ah1 of kt      | stages Bh1 of kt+1
    BARSEQ(4);
    READ_A(1, cur);
    STAGE(lB[nxt], gB, 1, kt + 1);
    CALC_SC(1, kt, sb0);
    MFMA8(1, 0);
    // ph3: no new LDS reads     | stages Ah1 of kt+1 (no barrier needed)
    STAGE(lA[nxt], gA, 1, kt + 1);
    CALC_SC(1, kt, sb1);
    MFMA8(1, 1);
  }
  { // last tile: no staging; drain counts shrink 4 -> 2 -> 0
    const int kt = KT - 1, cur = kt & 1;
    const float sb0 = sb[(bn * 2 + 0) * J + kt];
    const float sb1 = sb[(bn * 2 + 1) * J + kt];
    BARSEQ(4);
    READ_A(0, cur); READ_B(0, cur);
    CALC_SC(0, kt, sb0); MFMA8(0, 0);
    BARSEQ(2);
    READ_B(1, cur);
    CALC_SC(0, kt, sb1); MFMA8(0, 1);
    BARSEQ(0);
    READ_A(1, cur);
    CALC_SC(1, kt, sb0); MFMA8(1, 0);
    CALC_SC(1, kt, sb1); MFMA8(1, 1);
  }

  // epilogue: bias + store (C/D: col = r16, row = kg*4 + r)
  #pragma unroll
  for (int ng = 0; ng < 2; ++ng) {
    float bb[2];
    #pragma unroll
    for (int j = 0; j < 2; ++j)
      bb[j] = bias[bn * 256 + ng * 128 + wc * 32 + j * 16 + r16];
    #pragma unroll
    for (int mg = 0; mg < 2; ++mg) {
      #pragma unroll
      for (int i = 0; i < 4; ++i) {
        int row0 = bm * 256 + mg * 128 + wr * 64 + i * 16 + kg * 4;
        #pragma unroll
        for (int r = 0; r < 4; ++r) {
          float* orow = out + (size_t)(row0 + r) * N + bn * 256 + ng * 128 + wc * 32;
          #pragma unroll
          for (int j = 0; j < 2; ++j)
            orow[j * 16 + r16] = tot[mg * 4 + i][ng * 2 + j][r] + bb[j];
        }
      }
    }
  }
}

extern "C" void kernel_launch(void* const* d_in, const int* in_sizes, int n_in,
                              void* d_out, int out_size, void* d_ws, size_t ws_size,
                              hipStream_t stream) {
  const float* x    = (const float*)d_in[0];
  const float* wt   = (const float*)d_in[1];
  const float* wsc  = (const float*)d_in[2];
  const float* bias = (const float*)d_in[3];
  float* out = (float*)d_out;

  const int O = in_sizes[3];            // 2048
  const int H = in_sizes[1] / O;        // 2048
  const int M = in_sizes[0] / H;        // 16384

  uint8_t* xq = (uint8_t*)d_ws;                       // M*H bytes
  uint8_t* w8 = xq + (size_t)M * H;                   // O*H bytes
  float*   sa = (float*)(w8 + (size_t)O * H);         // M*(H/128) floats

  quant_x<<<M, 256, 0, stream>>>(x, xq, sa);
  int n8 = O * H / 8;
  conv_w<<<(n8 + 255) / 256, 256, 0, stream>>>(wt, w8, n8);
  int grid = (M / 256) * (O / 256);
  gemm_fp8<<<grid, 512, 0, stream>>>(xq, w8, sa, wsc, bias, out, M, O, H);
}

// Round 5
// 155.961 us; speedup vs baseline: 1.0152x; 1.0152x over previous
//
#include <hip/hip_runtime.h>
#include <cstdint>

#define FP8MAX 448.0f

typedef float f32x4 __attribute__((ext_vector_type(4)));
typedef int   i32x4 __attribute__((ext_vector_type(4)));
typedef int   i32x8 __attribute__((ext_vector_type(8)));

union frag8 { i32x8 v8; i32x4 v4[2]; };

__device__ __forceinline__ void gload_lds16(const void* g, void* l) {
  __builtin_amdgcn_global_load_lds(
      (const __attribute__((address_space(1))) unsigned int*)g,
      (__attribute__((address_space(3))) unsigned int*)l,
      16, 0, 0);
}

// ---------- quantize x rows: H=2048 floats -> fp8 bytes + per-128-group inv_scale ----------
__global__ __launch_bounds__(256) void quant_x(const float* __restrict__ x,
                                               uint8_t* __restrict__ xq,
                                               float* __restrict__ sa) {
  const int m = blockIdx.x;
  const int t = threadIdx.x;
  const float* xr = x + (size_t)m * 2048;
  float4 v0 = ((const float4*)xr)[t * 2];
  float4 v1 = ((const float4*)xr)[t * 2 + 1];
  float amax = fmaxf(fmaxf(fmaxf(fabsf(v0.x), fabsf(v0.y)), fmaxf(fabsf(v0.z), fabsf(v0.w))),
                     fmaxf(fmaxf(fabsf(v1.x), fabsf(v1.y)), fmaxf(fabsf(v1.z), fabsf(v1.w))));
  #pragma unroll
  for (int off = 1; off < 16; off <<= 1)
    amax = fmaxf(amax, __shfl_xor(amax, off));
  amax = fmaxf(amax, 1e-12f);
  float s   = FP8MAX / amax;   // same op order as reference
  float inv = 1.0f / s;
  if ((t & 15) == 0) sa[(size_t)m * 16 + (t >> 4)] = inv;
  float q[8] = {v0.x * s, v0.y * s, v0.z * s, v0.w * s,
                v1.x * s, v1.y * s, v1.z * s, v1.w * s};
  #pragma unroll
  for (int i = 0; i < 8; ++i) q[i] = fminf(fmaxf(q[i], -FP8MAX), FP8MAX);
  union { unsigned long long u; unsigned int w[2]; } pk;
  pk.w[0] = __builtin_amdgcn_cvt_pk_fp8_f32(q[0], q[1], 0, false);
  pk.w[0] = __builtin_amdgcn_cvt_pk_fp8_f32(q[2], q[3], pk.w[0], true);
  pk.w[1] = __builtin_amdgcn_cvt_pk_fp8_f32(q[4], q[5], 0, false);
  pk.w[1] = __builtin_amdgcn_cvt_pk_fp8_f32(q[6], q[7], pk.w[1], true);
  ((unsigned long long*)(xq + (size_t)m * 2048))[t] = pk.u;
}

// ---------- weight f32 -> fp8 (values are exactly fp8-representable; cast is exact) ----------
__global__ __launch_bounds__(256) void conv_w(const float* __restrict__ w,
                                              uint8_t* __restrict__ w8, int n8) {
  int i = blockIdx.x * 256 + threadIdx.x;
  if (i >= n8) return;
  float4 v0 = ((const float4*)w)[i * 2];
  float4 v1 = ((const float4*)w)[i * 2 + 1];
  union { unsigned long long u; unsigned int x[2]; } pk;
  pk.x[0] = __builtin_amdgcn_cvt_pk_fp8_f32(v0.x, v0.y, 0, false);
  pk.x[0] = __builtin_amdgcn_cvt_pk_fp8_f32(v0.z, v0.w, pk.x[0], true);
  pk.x[1] = __builtin_amdgcn_cvt_pk_fp8_f32(v1.x, v1.y, 0, false);
  pk.x[1] = __builtin_amdgcn_cvt_pk_fp8_f32(v1.z, v1.w, pk.x[1], true);
  ((unsigned long long*)w8)[i] = pk.u;
}

// ---------- block-scaled fp8 GEMM, 256x256 tile, 8 waves, 8-phase K-loop ----------
#define SAL_STRIDE 264

__global__ __launch_bounds__(512, 2) void gemm_fp8(
    const uint8_t* __restrict__ A, const uint8_t* __restrict__ Bw,
    const float* __restrict__ sa, const float* __restrict__ sb,
    const float* __restrict__ bias, float* __restrict__ out,
    int M, int N, int K) {
  const int J = K >> 7;               // 16
  const int nbn = N >> 8;             // 8
  int bid = blockIdx.x;
  int nwg = gridDim.x;
  if ((nwg & 7) == 0) {               // T1 XCD chunked swizzle
    int cpx = nwg >> 3;
    bid = (bid & 7) * cpx + (bid >> 3);
  }
  const int bn = bid % nbn;
  const int bm = bid / nbn;
  const int t = threadIdx.x;
  const int lane = t & 63;
  const int w = t >> 6;
  const int wr = w >> 2;              // 0..1  (M band)
  const int wc = w & 3;               // 0..3  (N band)
  const int r16 = lane & 15;
  const int kg = lane >> 4;

  __shared__ __align__(16) uint8_t lA[2][256 * 128];   // [buf][h*128+row][128B]
  __shared__ __align__(16) uint8_t lB[2][256 * 128];
  __shared__ __align__(16) float sal[16 * SAL_STRIDE];

  const uint8_t* gA = A + (size_t)bm * 256 * K;
  const uint8_t* gB = Bw + (size_t)bn * 256 * K;

  for (int i = t; i < 256 * 16; i += 512) {
    int row = i >> 4, j = i & 15;
    sal[j * SAL_STRIDE + row] = sa[((size_t)bm * 256 + row) * 16 + j];
  }

  const int rl = t >> 3;     // 0..63
  const int sg = t & 7;      // 16B segment

  // stage one half-tile (128 rows x 128B): 2 gload_lds per thread (= 2 vmcnt units)
  #define STAGE(ldst, gbase, h_, kt_) do {                                   \
    _Pragma("unroll")                                                        \
    for (int it_ = 0; it_ < 2; ++it_) {                                      \
      int r_ = it_ * 64 + rl;                                                \
      int gr_ = (h_) * 128 + r_;                                             \
      gload_lds16(gbase + (size_t)gr_ * K + ((kt_) << 7) +                   \
                      ((sg ^ (r_ & 7)) << 4),                                \
                  (ldst) + gr_ * 128 + sg * 16);                             \
    } } while (0)

  __syncthreads();   // sal visible; drains sal's global loads (vmcnt -> 0)

  // prologue FIFO: Ah0(0) Bh0(0) Ah1(0) Bh1(0) Ah0(1) Bh0(1)  = 12 vmcnt units
  STAGE(lA[0], gA, 0, 0);
  STAGE(lB[0], gB, 0, 0);
  STAGE(lA[0], gA, 1, 0);
  STAGE(lB[0], gB, 1, 0);
  STAGE(lA[1], gA, 0, 1);
  STAGE(lB[1], gB, 0, 1);

  f32x4 tot[8][4] = {};
  const f32x4 fz = {0.f, 0.f, 0.f, 0.f};
  frag8 av[4], bv[2][2];
  f32x4 scq[4];

  // barrier macros: fence AFTER s_barrier so no LDS read can hoist above it
  #define BAR1_VM8  do { asm volatile("s_waitcnt vmcnt(8)" ::: "memory");    \
                         __builtin_amdgcn_s_barrier();                       \
                         asm volatile("" ::: "memory"); } while (0)
  #define BAR1      do { __builtin_amdgcn_s_barrier();                       \
                         asm volatile("" ::: "memory"); } while (0)
  #define MID       do { asm volatile("s_waitcnt lgkmcnt(0)" ::: "memory");  \
                         __builtin_amdgcn_sched_barrier(0); } while (0)
  #define BAR2      do { __builtin_amdgcn_s_barrier();                       \
                         asm volatile("" ::: "memory"); } while (0)

  #define READ_A(mg_, buf_) do { _Pragma("unroll")                           \
    for (int i_ = 0; i_ < 4; ++i_) {                                         \
      int row_ = (mg_) * 128 + wr * 64 + i_ * 16 + r16;                      \
      const uint8_t* bp_ = &lA[buf_][row_ * 128];                            \
      int sw_ = (row_ & 7) << 4;                                             \
      av[i_].v4[0] = *(const i32x4*)(bp_ + ((kg * 32) ^ sw_));               \
      av[i_].v4[1] = *(const i32x4*)(bp_ + ((kg * 32 + 16) ^ sw_));          \
    } } while (0)

  #define READ_B(ng_, buf_) do { _Pragma("unroll")                           \
    for (int j_ = 0; j_ < 2; ++j_) {                                         \
      int row_ = (ng_) * 128 + wc * 32 + j_ * 16 + r16;                      \
      const uint8_t* bp_ = &lB[buf_][row_ * 128];                            \
      int sw_ = (row_ & 7) << 4;                                             \
      bv[ng_][j_].v4[0] = *(const i32x4*)(bp_ + ((kg * 32) ^ sw_));          \
      bv[ng_][j_].v4[1] = *(const i32x4*)(bp_ + ((kg * 32 + 16) ^ sw_));     \
    } } while (0)

  #define CALC_SC(mg_, kt_, sbj_) do { _Pragma("unroll")                     \
    for (int i_ = 0; i_ < 4; ++i_) {                                         \
      scq[i_] = (*(const f32x4*)&sal[(kt_) * SAL_STRIDE + (mg_) * 128 +      \
                                     wr * 64 + i_ * 16 + kg * 4]) * (sbj_);  \
    } } while (0)

  #define MFMA8(mg_, ng_) do {                                               \
    __builtin_amdgcn_s_setprio(1);                                           \
    _Pragma("unroll")                                                        \
    for (int i_ = 0; i_ < 4; ++i_) { _Pragma("unroll")                       \
      for (int j_ = 0; j_ < 2; ++j_) {                                       \
        f32x4 p_ = __builtin_amdgcn_mfma_scale_f32_16x16x128_f8f6f4(         \
            av[i_].v8, bv[ng_][j_].v8, fz, 0, 0, 0, 0x7f7f7f7f, 0,           \
            0x7f7f7f7f);                                                     \
        tot[(mg_) * 4 + i_][(ng_) * 2 + j_] += p_ * scq[i_];                 \
      } }                                                                    \
    __builtin_amdgcn_s_setprio(0); } while (0)

  const int KT = K >> 7;   // 16
  const int NI = KT >> 1;  // 8 double-K iterations
  // Uniform ring: ALL iterations stage the same count; stage K-indices wrap
  // mod KT on the last iterations (junk loads into already-consumed regions;
  // keeps the per-wave vmcnt FIFO identical every iteration).
  for (int i = 0; i < NI; ++i) {
    const int kt = 2 * i;                               // consumed this iter: kt, kt+1
    const int kt2 = (kt + 2 < KT) ? kt + 2 : kt + 2 - KT;
    const int kt3 = (kt + 3 < KT) ? kt + 3 : kt + 3 - KT;
    const float sb0  = sb[(bn * 2 + 0) * J + kt];
    const float sb1  = sb[(bn * 2 + 1) * J + kt];
    const float sb0n = sb[(bn * 2 + 0) * J + kt + 1];
    const float sb1n = sb[(bn * 2 + 1) * J + kt + 1];
    // ph0: consume Ah0,Bh0(kt) | stage Ah1,Bh1(kt+1)
    BAR1_VM8;
    READ_A(0, 0); READ_B(0, 0); CALC_SC(0, kt, sb0);
    STAGE(lA[1], gA, 1, kt + 1); STAGE(lB[1], gB, 1, kt + 1);
    MID; MFMA8(0, 0); BAR2;
    // ph1: consume Bh1(kt)
    BAR1_VM8;
    READ_B(1, 0); CALC_SC(0, kt, sb1);
    MID; MFMA8(0, 1); BAR2;
    // ph2: consume Ah1(kt) | stage Ah0(kt+2)
    BAR1;
    READ_A(1, 0); CALC_SC(1, kt, sb0);
    STAGE(lA[0], gA, 0, kt2);
    MID; MFMA8(1, 0); BAR2;
    // ph3: reuse av,bv1 | stage Bh0(kt+2)
    BAR1;
    CALC_SC(1, kt, sb1);
    STAGE(lB[0], gB, 0, kt2);
    MID; MFMA8(1, 1); BAR2;
    // ph4: consume Ah0,Bh0(kt+1) | stage Ah1,Bh1(kt+2)
    BAR1_VM8;
    READ_A(0, 1); READ_B(0, 1); CALC_SC(0, kt + 1, sb0n);
    STAGE(lA[0], gA, 1, kt2); STAGE(lB[0], gB, 1, kt2);
    MID; MFMA8(0, 0); BAR2;
    // ph5: consume Bh1(kt+1)
    BAR1_VM8;
    READ_B(1, 1); CALC_SC(0, kt + 1, sb1n);
    MID; MFMA8(0, 1); BAR2;
    // ph6: consume Ah1(kt+1) | stage Ah0(kt+3)
    BAR1;
    READ_A(1, 1); CALC_SC(1, kt + 1, sb0n);
    STAGE(lA[1], gA, 0, kt3);
    MID; MFMA8(1, 0); BAR2;
    // ph7: stage Bh0(kt+3)
    BAR1;
    CALC_SC(1, kt + 1, sb1n);
    STAGE(lB[1], gB, 0, kt3);
    MID; MFMA8(1, 1); BAR2;
  }
  // retire the 12 junk loads before touching anything else
  asm volatile("s_waitcnt vmcnt(0)" ::: "memory");

  // epilogue: bias + store (C/D: col = r16, row = kg*4 + r)
  #pragma unroll
  for (int ng = 0; ng < 2; ++ng) {
    float bb[2];
    #pragma unroll
    for (int j = 0; j < 2; ++j)
      bb[j] = bias[bn * 256 + ng * 128 + wc * 32 + j * 16 + r16];
    #pragma unroll
    for (int mg = 0; mg < 2; ++mg) {
      #pragma unroll
      for (int i = 0; i < 4; ++i) {
        int row0 = bm * 256 + mg * 128 + wr * 64 + i * 16 + kg * 4;
        #pragma unroll
        for (int r = 0; r < 4; ++r) {
          float* orow = out + (size_t)(row0 + r) * N + bn * 256 + ng * 128 + wc * 32;
          #pragma unroll
          for (int j = 0; j < 2; ++j)
            orow[j * 16 + r16] = tot[mg * 4 + i][ng * 2 + j][r] + bb[j];
        }
      }
    }
  }
}

extern "C" void kernel_launch(void* const* d_in, const int* in_sizes, int n_in,
                              void* d_out, int out_size, void* d_ws, size_t ws_size,
                              hipStream_t stream) {
  const float* x    = (const float*)d_in[0];
  const float* wt   = (const float*)d_in[1];
  const float* wsc  = (const float*)d_in[2];
  const float* bias = (const float*)d_in[3];
  float* out = (float*)d_out;

  const int O = in_sizes[3];            // 2048
  const int H = in_sizes[1] / O;        // 2048
  const int M = in_sizes[0] / H;        // 16384

  uint8_t* xq = (uint8_t*)d_ws;                       // M*H bytes
  uint8_t* w8 = xq + (size_t)M * H;                   // O*H bytes
  float*   sa = (float*)(w8 + (size_t)O * H);         // M*(H/128) floats

  quant_x<<<M, 256, 0, stream>>>(x, xq, sa);
  int n8 = O * H / 8;
  conv_w<<<(n8 + 255) / 256, 256, 0, stream>>>(wt, w8, n8);
  int grid = (M / 256) * (O / 256);
  gemm_fp8<<<grid, 512, 0, stream>>>(xq, w8, sa, wsc, bias, out, M, O, H);
}

// Round 6
// 142.091 us; speedup vs baseline: 1.1143x; 1.0976x over previous
//
#include <hip/hip_runtime.h>
#include <cstdint>

#define FP8MAX 448.0f

typedef float f32x4 __attribute__((ext_vector_type(4)));
typedef int   i32x4 __attribute__((ext_vector_type(4)));
typedef int   i32x8 __attribute__((ext_vector_type(8)));

union frag8 { i32x8 v8; i32x4 v4[2]; };

__device__ __forceinline__ void gload_lds16(const void* g, void* l) {
  __builtin_amdgcn_global_load_lds(
      (const __attribute__((address_space(1))) unsigned int*)g,
      (__attribute__((address_space(3))) unsigned int*)l,
      16, 0, 0);
}

// ---------- quantize x rows: H=2048 floats -> fp8 bytes + per-128-group inv_scale ----------
__global__ __launch_bounds__(256) void quant_x(const float* __restrict__ x,
                                               uint8_t* __restrict__ xq,
                                               float* __restrict__ sa) {
  const int m = blockIdx.x;
  const int t = threadIdx.x;
  const float* xr = x + (size_t)m * 2048;
  float4 v0 = ((const float4*)xr)[t * 2];
  float4 v1 = ((const float4*)xr)[t * 2 + 1];
  float amax = fmaxf(fmaxf(fmaxf(fabsf(v0.x), fabsf(v0.y)), fmaxf(fabsf(v0.z), fabsf(v0.w))),
                     fmaxf(fmaxf(fabsf(v1.x), fabsf(v1.y)), fmaxf(fabsf(v1.z), fabsf(v1.w))));
  #pragma unroll
  for (int off = 1; off < 16; off <<= 1)
    amax = fmaxf(amax, __shfl_xor(amax, off));
  amax = fmaxf(amax, 1e-12f);
  float s   = FP8MAX / amax;   // same op order as reference
  float inv = 1.0f / s;
  if ((t & 15) == 0) sa[(size_t)m * 16 + (t >> 4)] = inv;
  float q[8] = {v0.x * s, v0.y * s, v0.z * s, v0.w * s,
                v1.x * s, v1.y * s, v1.z * s, v1.w * s};
  #pragma unroll
  for (int i = 0; i < 8; ++i) q[i] = fminf(fmaxf(q[i], -FP8MAX), FP8MAX);
  union { unsigned long long u; unsigned int w[2]; } pk;
  pk.w[0] = __builtin_amdgcn_cvt_pk_fp8_f32(q[0], q[1], 0, false);
  pk.w[0] = __builtin_amdgcn_cvt_pk_fp8_f32(q[2], q[3], pk.w[0], true);
  pk.w[1] = __builtin_amdgcn_cvt_pk_fp8_f32(q[4], q[5], 0, false);
  pk.w[1] = __builtin_amdgcn_cvt_pk_fp8_f32(q[6], q[7], pk.w[1], true);
  ((unsigned long long*)(xq + (size_t)m * 2048))[t] = pk.u;
}

// ---------- weight f32 -> fp8 (values are exactly fp8-representable; cast is exact) ----------
__global__ __launch_bounds__(256) void conv_w(const float* __restrict__ w,
                                              uint8_t* __restrict__ w8, int n8) {
  int i = blockIdx.x * 256 + threadIdx.x;
  if (i >= n8) return;
  float4 v0 = ((const float4*)w)[i * 2];
  float4 v1 = ((const float4*)w)[i * 2 + 1];
  union { unsigned long long u; unsigned int x[2]; } pk;
  pk.x[0] = __builtin_amdgcn_cvt_pk_fp8_f32(v0.x, v0.y, 0, false);
  pk.x[0] = __builtin_amdgcn_cvt_pk_fp8_f32(v0.z, v0.w, pk.x[0], true);
  pk.x[1] = __builtin_amdgcn_cvt_pk_fp8_f32(v1.x, v1.y, 0, false);
  pk.x[1] = __builtin_amdgcn_cvt_pk_fp8_f32(v1.z, v1.w, pk.x[1], true);
  ((unsigned long long*)w8)[i] = pk.u;
}

// ---------- block-scaled fp8 GEMM: BM=BN=BK=128, 512 thr (8 waves 4x2),
// per-wave 32x64, counted-vmcnt double-buffer pipeline, 2 blocks/CU ----------
__global__ __launch_bounds__(512, 4) void gemm_fp8(
    const uint8_t* __restrict__ A, const uint8_t* __restrict__ Bw,
    const float* __restrict__ sa, const float* __restrict__ sb,
    const float* __restrict__ bias, float* __restrict__ out,
    int M, int N, int K) {
  const int J = K >> 7;               // 16
  const int nbn = N >> 7;             // 16
  int bid = blockIdx.x;
  int nwg = gridDim.x;
  if ((nwg & 7) == 0) {               // T1 XCD chunked swizzle
    int cpx = nwg >> 3;
    bid = (bid & 7) * cpx + (bid >> 3);
  }
  const int bn = bid % nbn;
  const int bm = bid / nbn;
  const int t = threadIdx.x;
  const int lane = t & 63;
  const int w = t >> 6;
  const int wr = w >> 1;              // 0..3  (M band, 32 rows each)
  const int wc = w & 1;               // 0..1  (N band, 64 cols each)
  const int r16 = lane & 15;
  const int kg = lane >> 4;

  __shared__ __align__(16) uint8_t lA[2][128 * 128];
  __shared__ __align__(16) uint8_t lB[2][128 * 128];
  __shared__ __align__(16) float sal[16 * 128];   // [j][row], 16B-aligned reads

  const uint8_t* gA = A + (size_t)bm * 128 * K;
  const uint8_t* gB = Bw + (size_t)bn * 128 * K;

  for (int i = t; i < 128 * 16; i += 512) {
    int row = i >> 4, j = i & 15;
    sal[j * 128 + row] = sa[((size_t)bm * 128 + row) * 16 + j];
  }

  const int rl = t >> 3;     // 0..63
  const int sg = t & 7;      // 16B segment

  // stage one full K-tile (A 16KB + B 16KB): 4 gload_lds per thread
  #define STAGE(buf_, kt_) do {                                              \
    _Pragma("unroll")                                                        \
    for (int it_ = 0; it_ < 2; ++it_) {                                      \
      int r_ = it_ * 64 + rl;                                                \
      int so_ = ((sg ^ (r_ & 7)) << 4);                                      \
      gload_lds16(gA + (size_t)r_ * K + ((kt_) << 7) + so_,                  \
                  &lA[buf_][r_ * 128 + sg * 16]);                            \
      gload_lds16(gB + (size_t)r_ * K + ((kt_) << 7) + so_,                  \
                  &lB[buf_][r_ * 128 + sg * 16]);                            \
    } } while (0)

  __syncthreads();   // sal visible; drains sal's global loads (vmcnt -> 0)

  STAGE(0, 0);       // 4 outstanding
  STAGE(1, 1);       // 8 outstanding

  f32x4 tot[2][4] = {};
  const f32x4 fz = {0.f, 0.f, 0.f, 0.f};
  frag8 av[2], bv[4];
  f32x4 scq[2];

  const int KT = K >> 7;   // 16
  for (int kt = 0; kt < KT; ++kt) {
    const int cur = kt & 1;
    // wait: everything except the most recent STAGE (tile kt+1) retired
    asm volatile("s_waitcnt vmcnt(4)" ::: "memory");
    __builtin_amdgcn_s_barrier();
    asm volatile("" ::: "memory");
    // fragment reads (register) + scales
    #pragma unroll
    for (int a = 0; a < 2; ++a) {
      int row = wr * 32 + a * 16 + r16;
      const uint8_t* bp = &lA[cur][row * 128];
      int sw = (row & 7) << 4;
      av[a].v4[0] = *(const i32x4*)(bp + ((kg * 32) ^ sw));
      av[a].v4[1] = *(const i32x4*)(bp + ((kg * 32 + 16) ^ sw));
    }
    #pragma unroll
    for (int b = 0; b < 4; ++b) {
      int row = wc * 64 + b * 16 + r16;
      const uint8_t* bp = &lB[cur][row * 128];
      int sw = (row & 7) << 4;
      bv[b].v4[0] = *(const i32x4*)(bp + ((kg * 32) ^ sw));
      bv[b].v4[1] = *(const i32x4*)(bp + ((kg * 32 + 16) ^ sw));
    }
    const float sbj = sb[bn * J + kt];
    #pragma unroll
    for (int a = 0; a < 2; ++a)
      scq[a] = (*(const f32x4*)&sal[kt * 128 + wr * 32 + a * 16 + kg * 4]) * sbj;
    // compute
    __builtin_amdgcn_s_setprio(1);
    #pragma unroll
    for (int a = 0; a < 2; ++a) {
      #pragma unroll
      for (int b = 0; b < 4; ++b) {
        f32x4 p = __builtin_amdgcn_mfma_scale_f32_16x16x128_f8f6f4(
            av[a].v8, bv[b].v8, fz, 0, 0, 0, 0x7f7f7f7f, 0, 0x7f7f7f7f);
        tot[a][b] += p * scq[a];
      }
    }
    __builtin_amdgcn_s_setprio(0);
    __builtin_amdgcn_s_barrier();      // all waves done reading buf[cur]
    asm volatile("" ::: "memory");
    // stage tile kt+2 into buf[cur] (wrapped junk on last 2 iters keeps
    // the vmcnt FIFO uniform; targets regions already consumed)
    const int kt2 = (kt + 2 < KT) ? kt + 2 : kt + 2 - KT;
    STAGE(cur, kt2);                   // back to 8 outstanding
  }
  asm volatile("s_waitcnt vmcnt(0)" ::: "memory");   // retire junk loads

  // epilogue: bias + store (C/D: col = r16, row = kg*4 + r)
  float bb[4];
  #pragma unroll
  for (int b = 0; b < 4; ++b) bb[b] = bias[bn * 128 + wc * 64 + b * 16 + r16];
  #pragma unroll
  for (int a = 0; a < 2; ++a) {
    int row0 = bm * 128 + wr * 32 + a * 16 + kg * 4;
    #pragma unroll
    for (int r = 0; r < 4; ++r) {
      float* orow = out + (size_t)(row0 + r) * N + bn * 128 + wc * 64;
      #pragma unroll
      for (int b = 0; b < 4; ++b)
        orow[b * 16 + r16] = tot[a][b][r] + bb[b];
    }
  }
}

extern "C" void kernel_launch(void* const* d_in, const int* in_sizes, int n_in,
                              void* d_out, int out_size, void* d_ws, size_t ws_size,
                              hipStream_t stream) {
  const float* x    = (const float*)d_in[0];
  const float* wt   = (const float*)d_in[1];
  const float* wsc  = (const float*)d_in[2];
  const float* bias = (const float*)d_in[3];
  float* out = (float*)d_out;

  const int O = in_sizes[3];            // 2048
  const int H = in_sizes[1] / O;        // 2048
  const int M = in_sizes[0] / H;        // 16384

  uint8_t* xq = (uint8_t*)d_ws;                       // M*H bytes
  uint8_t* w8 = xq + (size_t)M * H;                   // O*H bytes
  float*   sa = (float*)(w8 + (size_t)O * H);         // M*(H/128) floats

  quant_x<<<M, 256, 0, stream>>>(x, xq, sa);
  int n8 = O * H / 8;
  conv_w<<<(n8 + 255) / 256, 256, 0, stream>>>(wt, w8, n8);
  int grid = (M / 128) * (O / 128);
  gemm_fp8<<<grid, 512, 0, stream>>>(xq, w8, sa, wsc, bias, out, M, O, H);
}